// Round 9
// baseline (718.442 us; speedup 1.0000x reference)
//
#include <hip/hip_runtime.h>
#include <stdint.h>

typedef float    f32x4 __attribute__((ext_vector_type(4)));
typedef float    f32x2 __attribute__((ext_vector_type(2)));
typedef _Float16 f16x8 __attribute__((ext_vector_type(8)));
typedef _Float16 f16x4 __attribute__((ext_vector_type(4)));
typedef _Float16 f16x2 __attribute__((ext_vector_type(2)));

#define SEQ   2048
#define HIDD  2048
#define MROWS 4096
#define NQKV  12288          // 96 x 128, no pad
#define NCHUNK 32
#define CLEN   64

__device__ __forceinline__ void gload_lds16(const void* g, void* l) {
  __builtin_amdgcn_global_load_lds((const __attribute__((address_space(1))) uint32_t*)g,
                                   (__attribute__((address_space(3))) uint32_t*)l, 16, 0, 0);
}
// XOR swizzles (byte addressing) for bank-conflict-free f16 frag reads
__device__ __forceinline__ int swz256(int row, int colb) { return row * 256 + (colb ^ ((row & 7) << 4)); }
__device__ __forceinline__ int swz128(int row, int colb) { return row * 128 + (colb ^ ((row & 7) << 4)); }

// ---------------- A = (h * mask) -> fp16 ----------------
__global__ __launch_bounds__(256)
void amask_kernel(const float* __restrict__ h, const float* __restrict__ mask,
                  _Float16* __restrict__ A1) {
  int i = blockIdx.x * 256 + threadIdx.x;            // one float4 each
  if (i >= MROWS * HIDD / 4) return;
  f32x4 x = ((const f32x4*)h)[i];
  float m = mask[(i * 4) >> 11];
  f16x4 r;
  r[0] = (_Float16)(x[0] * m); r[1] = (_Float16)(x[1] * m);
  r[2] = (_Float16)(x[2] * m); r[3] = (_Float16)(x[3] * m);
  *(f16x4*)(A1 + (size_t)i * 4) = r;
}

// ---------------- transpose fp32 [R][C] -> fp16 [C][R] ----------------
__global__ __launch_bounds__(256)
void transpose_f16(const float* __restrict__ in, _Float16* __restrict__ out,
                   int R, int C) {
  __shared__ float tile[64][65];
  int c0 = blockIdx.x * 64, r0 = blockIdx.y * 64;
  int tx = threadIdx.x & 63, ty = threadIdx.x >> 6;
  #pragma unroll
  for (int i = 0; i < 16; ++i) {
    int r = i * 4 + ty;
    tile[r][tx] = in[(size_t)(r0 + r) * C + c0 + tx];
  }
  __syncthreads();
  #pragma unroll
  for (int i = 0; i < 16; ++i) {
    int c = i * 4 + ty;
    out[(size_t)(c0 + c) * R + r0 + tx] = (_Float16)tile[tx][c];
  }
}

// ---------------- BMx256 / BK=64 / 8-wave fp16 MFMA GEMM, balanced 4-phase ----------------
// C[M][N] = A[M][K] * Bt[N][K]^T.
// Per K-tile: tile-top {vmcnt(0); barrier} validates buf[cur]; then 4 phases with reads
// balanced 8/4/8/4, consumed same-phase: {reads -> barrier -> (compiler lgkmcnt) ->
// setprio MFMA x16 -> barrier}. Cross-wave FIFO stagger overlaps DS with MFMA.
// Staging for kt+1 issued in Ph0 (waited a full tile later). T2 swizzle via pre-swizzled
// global source column (LDS dest linear, read side applies same XOR). T1 XCD-swizzled grid.
#define SCHED0() __builtin_amdgcn_sched_barrier(0)
template <typename CT, int BM>
__global__ __launch_bounds__(512, 2)
void gemm4p(const _Float16* __restrict__ A, const _Float16* __restrict__ Bt,
            CT* __restrict__ C, int M, int N, int K, int tiles_n) {
  constexpr int RF  = BM / 32;          // row frags per wave (8 or 4)
  constexpr int RH  = RF / 2;           // frags per mh-half
  constexpr int AR  = BM / 8;           // A rows staged per wave
  constexpr int NA  = AR / 8;           // A stage insts per thread
  __shared__ __align__(16) _Float16 lsA[2][BM * 64];
  __shared__ __align__(16) _Float16 lsB[2][256 * 64];
  // T1: bijective XCD chunk swizzle (gridDim.x % 8 == 0)
  int cpx = gridDim.x >> 3;
  int lid = (blockIdx.x & 7) * cpx + (blockIdx.x >> 3);
  int bm = lid / tiles_n, bn = lid % tiles_n;
  int m0 = bm * BM, n0 = bn * 256;
  int tid = threadIdx.x;
  int w = tid >> 6, lane = tid & 63;
  int wm = w >> 2, wn = w & 3;          // wave tile: rows [wm*(BM/2),+BM/2), cols [wn*64,+64)
  int la = lane & 15, lk = lane >> 4;
  int sr = lane >> 3;                               // slab row 0..7
  int scb = ((lane & 7) << 4) ^ ((sr & 7) << 4);    // pre-swizzled source byte col
  int nkt = K >> 6;
  f32x4 acc[RF][4] = {};

  auto stage = [&](int kt, int buf) {
    const char* ga = (const char*)(A  + (size_t)(m0 + w * AR) * K + kt * 64);
    const char* gb = (const char*)(Bt + (size_t)(n0 + w * 32) * K + kt * 64);
    #pragma unroll
    for (int i = 0; i < NA; ++i)
      gload_lds16(ga + (size_t)(i * 8 + sr) * (K * 2) + scb, &lsA[buf][(w * AR + i * 8) * 64]);
    #pragma unroll
    for (int i = 0; i < 4; ++i)
      gload_lds16(gb + (size_t)(i * 8 + sr) * (K * 2) + scb, &lsB[buf][(w * 32 + i * 8) * 64]);
  };

#define READ_AF(dst, mh, kw)                                                       \
  _Pragma("unroll") for (int r = 0; r < RH; ++r) {                                 \
    int row_ = wm * (BM / 2) + ((mh) * RH + r) * 16 + la;                          \
    dst[r] = *(const f16x8*)(cA + row_ * 128 + (((kw) * 64 + lk * 16) ^ ((row_ & 7) << 4))); }
#define READ_BF(kw)                                                                \
  _Pragma("unroll") for (int j = 0; j < 4; ++j) {                                  \
    int row_ = wn * 64 + j * 16 + la;                                              \
    bf[j] = *(const f16x8*)(cB + row_ * 128 + (((kw) * 64 + lk * 16) ^ ((row_ & 7) << 4))); }
#define MFMA_PH(src, mh)                                                           \
  __builtin_amdgcn_s_setprio(1);                                                   \
  _Pragma("unroll") for (int r = 0; r < RH; ++r)                                   \
    _Pragma("unroll") for (int j = 0; j < 4; ++j)                                  \
      acc[(mh) * RH + r][j] =                                                      \
        __builtin_amdgcn_mfma_f32_16x16x32_f16(src[r], bf[j], acc[(mh) * RH + r][j], 0, 0, 0); \
  __builtin_amdgcn_s_setprio(0);

  stage(0, 0);

  int cur = 0;
  for (int kt = 0; kt < nkt; ++kt) {
    asm volatile("s_waitcnt vmcnt(0)" ::: "memory");   // buf[cur] loads landed (issued 1 tile ago)
    __builtin_amdgcn_s_barrier();
    SCHED0();
    const char* cA = (const char*)&lsA[cur][0];
    const char* cB = (const char*)&lsB[cur][0];
    f16x8 af0[RH], af1[RH], bf[4];
    // ---- Ph0: reads (bf@kw0 + af rows 0..RH-1 @kw0) + staging; MFMA (mh0, kw0)
    READ_BF(0); READ_AF(af0, 0, 0);
    if (kt + 1 < nkt) stage(kt + 1, cur ^ 1);
    SCHED0(); __builtin_amdgcn_s_barrier(); SCHED0();
    MFMA_PH(af0, 0);
    SCHED0(); __builtin_amdgcn_s_barrier(); SCHED0();
    // ---- Ph1: reads (af rows RH.. @kw0); MFMA (mh1, kw0)
    READ_AF(af1, 1, 0);
    SCHED0(); __builtin_amdgcn_s_barrier(); SCHED0();
    MFMA_PH(af1, 1);
    SCHED0(); __builtin_amdgcn_s_barrier(); SCHED0();
    // ---- Ph2: reads (bf@kw1 + af rows 0..RH-1 @kw1); MFMA (mh0, kw1)
    READ_BF(1); READ_AF(af0, 0, 1);
    SCHED0(); __builtin_amdgcn_s_barrier(); SCHED0();
    MFMA_PH(af0, 0);
    SCHED0(); __builtin_amdgcn_s_barrier(); SCHED0();
    // ---- Ph3: reads (af rows RH.. @kw1); MFMA (mh1, kw1); trailing barrier = tile top
    READ_AF(af1, 1, 1);
    SCHED0(); __builtin_amdgcn_s_barrier(); SCHED0();
    MFMA_PH(af1, 1);
    SCHED0();
    cur ^= 1;
  }

  #pragma unroll
  for (int f = 0; f < RF; ++f)
    #pragma unroll
    for (int j = 0; j < 4; ++j) {
      int col = n0 + wn * 64 + j * 16 + la;
      #pragma unroll
      for (int r = 0; r < 4; ++r) {
        int row = m0 + wm * (BM / 2) + f * 16 + lk * 4 + r;
        C[(size_t)row * N + col] = (CT)acc[f][j][r];
      }
    }
#undef READ_AF
#undef READ_BF
#undef MFMA_PH
}

// ---------------- ba = (h*mask) @ W_ba in fp32 (precision-critical for g) ----------------
__global__ __launch_bounds__(256)
void ba_gemm(const float* __restrict__ h, const float* __restrict__ mask,
             const float* __restrict__ Wba, float* __restrict__ ba) {
  __shared__ float red[4][8][64];
  int r0 = blockIdx.x * 8;
  int c = threadIdx.x & 63, kc = threadIdx.x >> 6;
  float acc[8] = {};
  const float* wp = Wba + (size_t)(kc * 512) * 64 + c;
  const float* hp = h + (size_t)r0 * HIDD + kc * 512;
  for (int i = 0; i < 512; ++i) {
    float w = wp[(size_t)i * 64];
    #pragma unroll
    for (int r = 0; r < 8; ++r)
      acc[r] += hp[(size_t)r * HIDD + i] * w;
  }
  #pragma unroll
  for (int r = 0; r < 8; ++r) red[kc][r][c] = acc[r];
  __syncthreads();
  if (kc == 0) {
    #pragma unroll
    for (int r = 0; r < 8; ++r) {
      float s = red[0][r][c] + red[1][r][c] + red[2][r][c] + red[3][r][c];
      ba[(size_t)(r0 + r) * 64 + c] = s * mask[r0 + r];
    }
  }
}

// ---------------- conv(4-tap causal) + SiLU + l2norm -> qn16, kn16, vb16 ----------------
__global__ __launch_bounds__(256)
void conv_kernel(const _Float16* __restrict__ qkvz, const float* __restrict__ ck,
                 _Float16* __restrict__ qn, _Float16* __restrict__ kn,
                 _Float16* __restrict__ vb) {
  int row = blockIdx.x;               // b*2048 + t
  int b = row >> 11, t = row & 2047;
  int lane = threadIdx.x & 63, wid = threadIdx.x >> 6;
  for (int u = wid; u < 64; u += 4) {
    int c, cc, hh;
    if (u < 16)      { hh = u;      c = hh * 768;                               cc = hh * 128; }
    else if (u < 32) { hh = u - 16; c = hh * 768 + 128;                         cc = 2048 + hh * 128; }
    else             { hh = u - 32; c = (hh >> 1) * 768 + 256 + (hh & 1) * 128; cc = 4096 + hh * 128; }
    float y0 = 0.f, y1 = 0.f;
    #pragma unroll
    for (int j = 0; j < 4; ++j) {
      int tt = t - 3 + j;
      if (tt >= 0) {
        const _Float16* r = qkvz + (size_t)(b * 2048 + tt) * NQKV + c;
        f16x2 x = *(const f16x2*)(r + 2 * lane);
        f32x2 w = *(const f32x2*)(ck + j * 8192 + cc + 2 * lane);
        y0 += (float)x[0] * w[0];
        y1 += (float)x[1] * w[1];
      }
    }
    y0 = y0 / (1.f + expf(-y0));
    y1 = y1 / (1.f + expf(-y1));
    if (u < 32) {
      float ss = y0 * y0 + y1 * y1;
      #pragma unroll
      for (int m = 1; m < 64; m <<= 1) ss += __shfl_xor(ss, m);
      float rs = rsqrtf(ss + 1e-6f);
      if (u < 16) rs *= 0.08838834764831845f;   // DK^-0.5
      y0 *= rs; y1 *= rs;
      _Float16* dst = (u < 16 ? qn : kn) + (size_t)row * 2048 + hh * 128;
      f16x2 o; o[0] = (_Float16)y0; o[1] = (_Float16)y1;
      *(f16x2*)(dst + 2 * lane) = o;
    } else {
      _Float16* dst = vb + (size_t)row * 4096 + hh * 128;
      f16x2 o; o[0] = (_Float16)y0; o[1] = (_Float16)y1;
      *(f16x2*)(dst + 2 * lane) = o;
    }
  }
}

// ---------------- g/beta from fp32 ba; outputs TRANSPOSED [vh][b*2048+t] ----------------
__global__ __launch_bounds__(256)
void egbeta_kernel(const float* __restrict__ ba, const float* __restrict__ Alog,
                   const float* __restrict__ dtb, float* __restrict__ gout,
                   float* __restrict__ bout) {
  int i = blockIdx.x * 256 + threadIdx.x;     // MROWS*32
  if (i >= MROWS * 32) return;
  int vh = i >> 12, row = i & 4095;
  int kh = vh >> 1, r = vh & 1;
  const float* p = ba + (size_t)row * 64 + kh * 4;
  float bv = p[r], av = p[2 + r];
  float x = av + dtb[vh];
  float sp = (x > 20.f) ? x : log1pf(expf(x));
  gout[(size_t)vh * MROWS + row] = -expf(Alog[vh]) * sp;
  bout[(size_t)vh * MROWS + row] = 1.f / (1.f + expf(-bv));
}

// ---------------- chunked gated delta-rule scan (UT transform, MFMA, 8 waves) ----------------
__global__ __launch_bounds__(512, 2)
void chunk_scan(const _Float16* __restrict__ qn, const _Float16* __restrict__ kn,
                _Float16* __restrict__ vb, const float* __restrict__ gb,
                const float* __restrict__ btb) {
  __shared__ __align__(16) _Float16 Ks[64 * 128];   // [t][k] swz256
  __shared__ __align__(16) _Float16 Qs[64 * 128];   // [t][k] swz256
  __shared__ __align__(16) _Float16 Kt[128 * 64];   // [k][s] swz128
  __shared__ __align__(16) _Float16 Sf[32 * 128];   // [v][k] f16 state copy, swz256
  __shared__ float AT[64 * 65];                     // AT[s][t] = A[t][s]
  __shared__ __align__(16) _Float16 M16[64 * 64];   // [t][s] swz128
  __shared__ float RHS[32 * 65];                    // [v][t]
  __shared__ __align__(16) _Float16 Uv[32 * 64];    // [v][s] swz128 (raw u)
  __shared__ __align__(16) _Float16 Ub[32 * 64];    // [v][s] swz128 (u * scU[s])
  __shared__ __align__(16) _Float16 Vb[64 * 32];    // [t][v] linear, 64B rows
  __shared__ float gs[64], bs[64], cgs[64], bexp[64], scU[64];

  char* Ksb = (char*)Ks; char* Qsb = (char*)Qs; char* Ktb = (char*)Kt;
  char* Sfb = (char*)Sf; char* M16b = (char*)M16;
  char* Uvb = (char*)Uv; char* Ubb = (char*)Ub; char* Vbb = (char*)Vb;

  int bid = blockIdx.x;
  int b = bid >> 7, vh = (bid >> 2) & 31, vsl = bid & 3;
  int kh = vh >> 1;
  int tid = threadIdx.x;
  int w = tid >> 6, lane = tid & 63;
  int wr = w >> 1, wc = w & 1;
  int la = lane & 15, lk = lane >> 4;

  const _Float16* kgb = kn + (size_t)(b * 2048) * 2048 + kh * 128;
  const _Float16* qgb = qn + (size_t)(b * 2048) * 2048 + kh * 128;
  _Float16*       vgb = vb + (size_t)(b * 2048) * 4096 + vh * 128 + vsl * 32;
  const float*    ggb = gb  + (size_t)vh * MROWS + b * 2048;
  const float*    bgb = btb + (size_t)vh * MROWS + b * 2048;

  int srow = tid >> 3, sseg = tid & 7;
  int tk = tid & 127, tth = tid >> 7;

  f16x8 kr[2], qr[2]; f16x4 vr; float ebr;
  float sreg[2][4] = {};                 // S[v = vt*16+lk*4+r][k = w*16+la]

  { f32x4 z = {}; ((f32x4*)Sf)[tid] = z; }

  kr[0] = *(const f16x8*)(kgb + (size_t)srow * 2048 + sseg * 16);
  kr[1] = *(const f16x8*)(kgb + (size_t)srow * 2048 + sseg * 16 + 8);
  qr[0] = *(const f16x8*)(qgb + (size_t)srow * 2048 + sseg * 16);
  qr[1] = *(const f16x8*)(qgb + (size_t)srow * 2048 + sseg * 16 + 8);
  vr    = *(const f16x4*)(vgb + (size_t)srow * 4096 + sseg * 4);
  ebr   = (tid < 64) ? ggb[tid] : (tid < 128 ? bgb[tid - 64] : 0.f);
  *(f16x8*)(Ksb + swz256(srow, sseg * 32))      = kr[0];
  *(f16x8*)(Ksb + swz256(srow, sseg * 32 + 16)) = kr[1];
  *(f16x8*)(Qsb + swz256(srow, sseg * 32))      = qr[0];
  *(f16x8*)(Qsb + swz256(srow, sseg * 32 + 16)) = qr[1];
  *(f16x4*)(Vbb + srow * 64 + sseg * 8) = vr;
  if (tid < 64) gs[tid] = ebr; else if (tid < 128) bs[tid - 64] = ebr;
  __syncthreads();

  #pragma unroll 1
  for (int c = 0; c < NCHUNK; ++c) {
    int cn = (c < NCHUNK - 1) ? c + 1 : c;
    kr[0] = *(const f16x8*)(kgb + (size_t)(cn * 64 + srow) * 2048 + sseg * 16);
    kr[1] = *(const f16x8*)(kgb + (size_t)(cn * 64 + srow) * 2048 + sseg * 16 + 8);
    qr[0] = *(const f16x8*)(qgb + (size_t)(cn * 64 + srow) * 2048 + sseg * 16);
    qr[1] = *(const f16x8*)(qgb + (size_t)(cn * 64 + srow) * 2048 + sseg * 16 + 8);
    vr    = *(const f16x4*)(vgb + (size_t)(cn * 64 + srow) * 4096 + sseg * 4);
    ebr   = (tid < 64) ? ggb[cn * 64 + tid] : (tid < 128 ? bgb[cn * 64 + tid - 64] : 0.f);

    f32x4 kk[2] = {}, qk[2] = {}, ks0 = {}, qs0 = {};
    #pragma unroll
    for (int ks = 0; ks < 4; ++ks) {
      f16x8 aK = *(const f16x8*)(Ksb + swz256(wr * 16 + la, ks * 64 + lk * 16));
      f16x8 aQ = *(const f16x8*)(Qsb + swz256(wr * 16 + la, ks * 64 + lk * 16));
      f16x8 bS = *(const f16x8*)(Sfb + swz256(wc * 16 + la, ks * 64 + lk * 16));
      #pragma unroll
      for (int j = 0; j < 2; ++j) {
        f16x8 bK = *(const f16x8*)(Ksb + swz256(wc * 32 + j * 16 + la, ks * 64 + lk * 16));
        kk[j] = __builtin_amdgcn_mfma_f32_16x16x32_f16(aK, bK, kk[j], 0, 0, 0);
        qk[j] = __builtin_amdgcn_mfma_f32_16x16x32_f16(aQ, bK, qk[j], 0, 0, 0);
      }
      ks0 = __builtin_amdgcn_mfma_f32_16x16x32_f16(aK, bS, ks0, 0, 0, 0);
      qs0 = __builtin_amdgcn_mfma_f32_16x16x32_f16(aQ, bS, qs0, 0, 0, 0);
    }
    {
      f16x8 r0, r1;
      #pragma unroll
      for (int j = 0; j < 8; ++j) {
        r0[j] = *(const _Float16*)(Ksb + swz256(tth * 16 + j, 2 * tk));
        r1[j] = *(const _Float16*)(Ksb + swz256(tth * 16 + 8 + j, 2 * tk));
      }
      *(f16x8*)(Ktb + swz128(tk, tth * 32))      = r0;
      *(f16x8*)(Ktb + swz128(tk, tth * 32 + 16)) = r1;
    }
    if (w == 0) {
      float g = gs[lane];
      #pragma unroll
      for (int off = 1; off < 64; off <<= 1) {
        float y = __shfl_up(g, off);
        if (lane >= off) g += y;
      }
      cgs[lane] = g;
      float cgL = __shfl(g, 63);
      bexp[lane] = __expf(g);
      scU[lane] = bs[lane] * __expf(cgL - g);
    }
    __syncthreads();   // B1

    {
      float cgt[4];
      #pragma unroll
      for (int r = 0; r < 4; ++r) cgt[r] = cgs[wr * 16 + lk * 4 + r];
      #pragma unroll
      for (int j = 0; j < 2; ++j) {
        int s = wc * 32 + j * 16 + la;
        float bsv = bs[s], cgss = cgs[s];
        #pragma unroll
        for (int r = 0; r < 4; ++r) {
          int t = wr * 16 + lk * 4 + r;
          float e = bsv * __expf(cgt[r] - cgss);
          AT[s * 65 + t] = (s < t) ? e * kk[j][r] : 0.f;
          float mm = (s <= t) ? e * qk[j][r] : 0.f;
          *(_Float16*)(M16b + swz128(t, s * 2)) = (_Float16)mm;
        }
      }
      #pragma unroll
      for (int r = 0; r < 4; ++r) {
        int t = wr * 16 + lk * 4 + r;
        int v = wc * 16 + la;
        float be = bexp[t];
        qs0[r] *= be;
        float vv = (float)*(const _Float16*)(Vbb + t * 64 + v * 2);
        RHS[v * 65 + t] = vv - be * ks0[r];
      }
    }
    __syncthreads();   // B2

    {
      float u[4];
      #pragma unroll
      for (int vi = 0; vi < 4; ++vi) u[vi] = RHS[(w * 4 + vi) * 65 + lane];
      #pragma unroll 1
      for (int sb = 0; sb < 8; ++sb) {
        float Ac[8];
        #pragma unroll
        for (int j = 0; j < 8; ++j) Ac[j] = AT[(sb * 8 + j) * 65 + lane];
        #pragma unroll
        for (int j = 0; j < 8; ++j) {
          int s = sb * 8 + j;
          #pragma unroll
          for (int vi = 0; vi < 4; ++vi) {
            float ubv = __builtin_bit_cast(float,
                __builtin_amdgcn_readlane(__builtin_bit_cast(int, u[vi]), s));
            u[vi] = fmaf(-Ac[j], ubv, u[vi]);
          }
        }
      }
      float sc = scU[lane];
      #pragma unroll
      for (int vi = 0; vi < 4; ++vi) {
        int v = w * 4 + vi;
        *(_Float16*)(Uvb + swz128(v, lane * 2)) = (_Float16)u[vi];
        *(_Float16*)(Ubb + swz128(v, lane * 2)) = (_Float16)(u[vi] * sc);
      }
    }
    __syncthreads();   // B3

    #pragma unroll
    for (int ss = 0; ss < 2; ++ss) {
      f16x8 aM = *(const f16x8*)(M16b + swz128(wr * 16 + la, ss * 64 + lk * 16));
      f16x8 bU = *(const f16x8*)(Uvb + swz128(wc * 16 + la, ss * 64 + lk * 16));
      qs0 = __builtin_amdgcn_mfma_f32_16x16x32_f16(aM, bU, qs0, 0, 0, 0);
    }
    #pragma unroll
    for (int r = 0; r < 4; ++r) {
      int t = wr * 16 + lk * 4 + r;
      vgb[(size_t)(c * 64 + t) * 4096 + wc * 16 + la] = (_Float16)qs0[r];  // in-place: v[t] dead
    }
    {
      f32x4 sd[2] = {};
      #pragma unroll
      for (int ss = 0; ss < 2; ++ss) {
        f16x8 bK = *(const f16x8*)(Ktb + swz128(w * 16 + la, ss * 64 + lk * 16));
        #pragma unroll
        for (int vt = 0; vt < 2; ++vt) {
          f16x8 aU = *(const f16x8*)(Ubb + swz128(vt * 16 + la, ss * 64 + lk * 16));
          sd[vt] = __builtin_amdgcn_mfma_f32_16x16x32_f16(aU, bK, sd[vt], 0, 0, 0);
        }
      }
      float beC = bexp[63];
      #pragma unroll
      for (int vt = 0; vt < 2; ++vt)
        #pragma unroll
        for (int r = 0; r < 4; ++r) {
          int v = vt * 16 + lk * 4 + r;
          int k = w * 16 + la;
          float sn = fmaf(sreg[vt][r], beC, sd[vt][r]);
          sreg[vt][r] = sn;
          *(_Float16*)(Sfb + swz256(v, k * 2)) = (_Float16)sn;
        }
    }
    __syncthreads();   // B4

    *(f16x8*)(Ksb + swz256(srow, sseg * 32))      = kr[0];
    *(f16x8*)(Ksb + swz256(srow, sseg * 32 + 16)) = kr[1];
    *(f16x8*)(Qsb + swz256(srow, sseg * 32))      = qr[0];
    *(f16x8*)(Qsb + swz256(srow, sseg * 32 + 16)) = qr[1];
    *(f16x4*)(Vbb + srow * 64 + sseg * 8) = vr;
    if (tid < 64) gs[tid] = ebr; else if (tid < 128) bs[tid - 64] = ebr;
    __syncthreads();   // B5
  }
}

// ---------------- RMSNorm * norm_kernel * silu(z) -> fp16 Ag ----------------
__global__ __launch_bounds__(256)
void gate_kernel(const _Float16* __restrict__ ob, const _Float16* __restrict__ qkvz,
                 const float* __restrict__ nk, _Float16* __restrict__ Ag) {
  int row = blockIdx.x;
  int lane = threadIdx.x & 63, wid = threadIdx.x >> 6;
  for (int vh = wid; vh < 32; vh += 4) {
    const _Float16* op = ob + (size_t)row * 4096 + vh * 128;
    f16x2 xx = *(const f16x2*)(op + 2 * lane);
    float x0 = (float)xx[0], x1 = (float)xx[1];
    float ss = x0 * x0 + x1 * x1;
    #pragma unroll
    for (int m = 1; m < 64; m <<= 1) ss += __shfl_xor(ss, m);
    float rs = rsqrtf(ss * (1.f / 128.f) + 1e-6f);
    f32x2 nv = *(const f32x2*)(nk + 2 * lane);
    float v0 = x0 * rs * nv[0], v1 = x1 * rs * nv[1];
    const _Float16* zp = qkvz + (size_t)row * NQKV + (vh >> 1) * 768 + 512 + (vh & 1) * 128;
    f16x2 zz = *(const f16x2*)(zp + 2 * lane);
    float z0 = (float)zz[0], z1 = (float)zz[1];
    v0 *= z0 / (1.f + expf(-z0));
    v1 *= z1 / (1.f + expf(-z1));
    _Float16* dst = Ag + (size_t)row * 4096 + vh * 128;
    f16x2 o; o[0] = (_Float16)v0; o[1] = (_Float16)v1;
    *(f16x2*)(dst + 2 * lane) = o;
  }
}

extern "C" void kernel_launch(void* const* d_in, const int* in_sizes, int n_in,
                              void* d_out, int out_size, void* d_ws, size_t ws_size,
                              hipStream_t stream) {
  const float* h     = (const float*)d_in[0];
  const float* mask  = (const float*)d_in[1];
  const float* Wqkvz = (const float*)d_in[2];
  const float* Wba   = (const float*)d_in[3];
  const float* ck    = (const float*)d_in[4];
  const float* Alog  = (const float*)d_in[5];
  const float* dtb   = (const float*)d_in[6];
  const float* nk    = (const float*)d_in[7];
  const float* Wout  = (const float*)d_in[8];
  float* out = (float*)d_out;

  char* w = (char*)d_ws;
  const size_t o_qkvz = 0;                         // 100,663,296  [gemm1 .. gate]
  const size_t o_A1   = 100663296;                 //  16,777,216  [amask .. gemm1]
  const size_t o_Bt1  = o_A1 + 16777216;           //  50,331,648  [transpose .. gemm1]
  const size_t o_ba   = o_Bt1 + 50331648;          //   1,048,576
  const size_t o_g    = o_ba + 1048576;            //     524,288
  const size_t o_bt   = o_g + 524288;              //     524,288
  const size_t total  = o_bt + 524288;             // 169,869,312 B = 162 MiB
  if (ws_size < total) return;

  _Float16* qkvz16 = (_Float16*)(w + o_qkvz);
  _Float16* A1     = (_Float16*)(w + o_A1);
  _Float16* Bt1    = (_Float16*)(w + o_Bt1);
  float*    ba32   = (float*)   (w + o_ba);
  float*    gbuf   = (float*)   (w + o_g);
  float*    btb    = (float*)   (w + o_bt);
  // aliases over dead regions:
  _Float16* qn16 = (_Float16*)(w + o_A1);                    // over A1 (dead after gemm1)
  _Float16* kn16 = (_Float16*)(w + o_Bt1);                   // over Bt1[0:16M)
  _Float16* vb16 = (_Float16*)(w + o_Bt1 + 16777216);        // over Bt1[16M:50M); o in-place
  _Float16* Ag   = (_Float16*)(w + o_A1);                    // over qn+kn (dead after scan)
  _Float16* Wt2  = (_Float16*)(w + 0);                       // over qkvz (dead after gate)

  amask_kernel<<<MROWS * HIDD / 4 / 256, 256, 0, stream>>>(h, mask, A1);
  transpose_f16<<<dim3(192, 32), 256, 0, stream>>>(Wqkvz, Bt1, HIDD, NQKV);
  ba_gemm<<<MROWS / 8, 256, 0, stream>>>(h, mask, Wba, ba32);
  gemm4p<_Float16, 256><<<16 * 48, 512, 0, stream>>>(A1, Bt1, qkvz16, MROWS, NQKV, HIDD, 48);
  conv_kernel<<<MROWS, 256, 0, stream>>>(qkvz16, ck, qn16, kn16, vb16);
  egbeta_kernel<<<MROWS * 32 / 256, 256, 0, stream>>>(ba32, Alog, dtb, gbuf, btb);
  chunk_scan<<<256, 512, 0, stream>>>(qn16, kn16, vb16, gbuf, btb);
  gate_kernel<<<MROWS, 256, 0, stream>>>(vb16, qkvz16, nk, Ag);
  transpose_f16<<<dim3(32, 64), 256, 0, stream>>>(Wout, Wt2, 4096, HIDD);
  gemm4p<float, 128><<<32 * 8, 512, 0, stream>>>(Ag, Wt2, out, MROWS, HIDD, 4096, 8);
}

// Round 10
// 658.411 us; speedup vs baseline: 1.0912x; 1.0912x over previous
//
#include <hip/hip_runtime.h>
#include <stdint.h>

typedef float    f32x4 __attribute__((ext_vector_type(4)));
typedef float    f32x2 __attribute__((ext_vector_type(2)));
typedef _Float16 f16x8 __attribute__((ext_vector_type(8)));
typedef _Float16 f16x4 __attribute__((ext_vector_type(4)));
typedef _Float16 f16x2 __attribute__((ext_vector_type(2)));

#define SEQ   2048
#define HIDD  2048
#define MROWS 4096
#define NQKV  12288          // 96 x 128, no pad
#define NCHUNK 32
#define CLEN   64

__device__ __forceinline__ void gload_lds16(const void* g, void* l) {
  __builtin_amdgcn_global_load_lds((const __attribute__((address_space(1))) uint32_t*)g,
                                   (__attribute__((address_space(3))) uint32_t*)l, 16, 0, 0);
}
// XOR swizzles (byte addressing) for bank-conflict-free f16 frag reads
__device__ __forceinline__ int swz256(int row, int colb) { return row * 256 + (colb ^ ((row & 7) << 4)); }
__device__ __forceinline__ int swz128(int row, int colb) { return row * 128 + (colb ^ ((row & 7) << 4)); }

// ---------------- A = (h * mask) -> fp16 ----------------
__global__ __launch_bounds__(256)
void amask_kernel(const float* __restrict__ h, const float* __restrict__ mask,
                  _Float16* __restrict__ A1) {
  int i = blockIdx.x * 256 + threadIdx.x;            // one float4 each
  if (i >= MROWS * HIDD / 4) return;
  f32x4 x = ((const f32x4*)h)[i];
  float m = mask[(i * 4) >> 11];
  f16x4 r;
  r[0] = (_Float16)(x[0] * m); r[1] = (_Float16)(x[1] * m);
  r[2] = (_Float16)(x[2] * m); r[3] = (_Float16)(x[3] * m);
  *(f16x4*)(A1 + (size_t)i * 4) = r;
}

// ---------------- transpose fp32 [R][C] -> fp16 [C][R] ----------------
__global__ __launch_bounds__(256)
void transpose_f16(const float* __restrict__ in, _Float16* __restrict__ out,
                   int R, int C) {
  __shared__ float tile[64][65];
  int c0 = blockIdx.x * 64, r0 = blockIdx.y * 64;
  int tx = threadIdx.x & 63, ty = threadIdx.x >> 6;
  #pragma unroll
  for (int i = 0; i < 16; ++i) {
    int r = i * 4 + ty;
    tile[r][tx] = in[(size_t)(r0 + r) * C + c0 + tx];
  }
  __syncthreads();
  #pragma unroll
  for (int i = 0; i < 16; ++i) {
    int c = i * 4 + ty;
    out[(size_t)(c0 + c) * R + r0 + tx] = (_Float16)tile[tx][c];
  }
}

// ---------------- BMx256 / BK=64 / 8-wave fp16 MFMA GEMM, 8-phase schedule ----------------
// (round-8 proven version: 211 us, MfmaUtil 43.5%, 0 bank conflicts, default XCD mapping
//  which is B-panel-affine since tiles_n % 8 == 0 — do NOT swizzle blockIdx.)
template <typename CT, int BM>
__global__ __launch_bounds__(512, 2)
void gemm8p(const _Float16* __restrict__ A, const _Float16* __restrict__ Bt,
            CT* __restrict__ C, int M, int N, int K, int tiles_n) {
  constexpr int RF  = BM / 32;          // row frags per wave (8 or 4)
  constexpr int RH  = RF / 2;           // frags per pm-half
  constexpr int AR  = BM / 8;           // A rows staged per wave
  constexpr int NA  = AR / 8;           // A stage insts per thread
  __shared__ __align__(16) _Float16 lsA[2][BM * 64];
  __shared__ __align__(16) _Float16 lsB[2][256 * 64];
  int bm = blockIdx.x / tiles_n, bn = blockIdx.x % tiles_n;
  int m0 = bm * BM, n0 = bn * 256;
  int tid = threadIdx.x;
  int w = tid >> 6, lane = tid & 63;
  int wm = w >> 2, wn = w & 3;          // wave tile: rows [wm*(BM/2),+BM/2), cols [wn*64,+64)
  int la = lane & 15, lk = lane >> 4;
  int sr = lane >> 3;                               // slab row 0..7
  int scb = ((lane & 7) << 4) ^ ((sr & 7) << 4);    // pre-swizzled source byte col
  int nkt = K >> 6;
  f32x4 acc[RF][4] = {};

  auto stage = [&](int kt, int buf) {
    const char* ga = (const char*)(A  + (size_t)(m0 + w * AR) * K + kt * 64);
    const char* gb = (const char*)(Bt + (size_t)(n0 + w * 32) * K + kt * 64);
    #pragma unroll
    for (int i = 0; i < NA; ++i)
      gload_lds16(ga + (size_t)(i * 8 + sr) * (K * 2) + scb, &lsA[buf][(w * AR + i * 8) * 64]);
    #pragma unroll
    for (int i = 0; i < 4; ++i)
      gload_lds16(gb + (size_t)(i * 8 + sr) * (K * 2) + scb, &lsB[buf][(w * 32 + i * 8) * 64]);
  };

  stage(0, 0);

  int cur = 0;
  for (int kt = 0; kt < nkt; ++kt) {
    asm volatile("s_waitcnt vmcnt(0)" ::: "memory");   // buf[cur] loads landed (issued 1 tile ago)
    __builtin_amdgcn_s_barrier();                      // all waves' loads done
    __builtin_amdgcn_sched_barrier(0);
    const char* cA = (const char*)&lsA[cur][0];
    const char* cB = (const char*)&lsB[cur][0];
    f16x8 bf[4][2], af[RH][2];
    // ---- P(0,0): read all bf + af half 0; issue staging; MFMA quadrant (0, cols 0-1)
    #pragma unroll
    for (int j = 0; j < 4; ++j)
      #pragma unroll
      for (int kw = 0; kw < 2; ++kw) {
        int row = wn * 64 + j * 16 + la;
        bf[j][kw] = *(const f16x8*)(cB + row * 128 + ((kw * 64 + lk * 16) ^ ((row & 7) << 4)));
      }
    #pragma unroll
    for (int r = 0; r < RH; ++r)
      #pragma unroll
      for (int kw = 0; kw < 2; ++kw) {
        int row = wm * (BM / 2) + r * 16 + la;
        af[r][kw] = *(const f16x8*)(cA + row * 128 + ((kw * 64 + lk * 16) ^ ((row & 7) << 4)));
      }
    if (kt + 1 < nkt) stage(kt + 1, cur ^ 1);
    __builtin_amdgcn_s_barrier();
    __builtin_amdgcn_sched_barrier(0);
    __builtin_amdgcn_s_setprio(1);
    #pragma unroll
    for (int r = 0; r < RH; ++r)
      #pragma unroll
      for (int j = 0; j < 2; ++j)
        #pragma unroll
        for (int kw = 0; kw < 2; ++kw)
          acc[r][j] = __builtin_amdgcn_mfma_f32_16x16x32_f16(af[r][kw], bf[j][kw], acc[r][j], 0, 0, 0);
    __builtin_amdgcn_s_setprio(0);
    __builtin_amdgcn_s_barrier();
    __builtin_amdgcn_sched_barrier(0);
    // ---- P(0,1): cols 2-3
    __builtin_amdgcn_s_setprio(1);
    #pragma unroll
    for (int r = 0; r < RH; ++r)
      #pragma unroll
      for (int j = 2; j < 4; ++j)
        #pragma unroll
        for (int kw = 0; kw < 2; ++kw)
          acc[r][j] = __builtin_amdgcn_mfma_f32_16x16x32_f16(af[r][kw], bf[j][kw], acc[r][j], 0, 0, 0);
    __builtin_amdgcn_s_setprio(0);
    __builtin_amdgcn_s_barrier();
    __builtin_amdgcn_sched_barrier(0);
    // ---- P(1,0): refill af with half 1; cols 0-1
    #pragma unroll
    for (int r = 0; r < RH; ++r)
      #pragma unroll
      for (int kw = 0; kw < 2; ++kw) {
        int row = wm * (BM / 2) + (RH + r) * 16 + la;
        af[r][kw] = *(const f16x8*)(cA + row * 128 + ((kw * 64 + lk * 16) ^ ((row & 7) << 4)));
      }
    __builtin_amdgcn_s_barrier();
    __builtin_amdgcn_sched_barrier(0);
    __builtin_amdgcn_s_setprio(1);
    #pragma unroll
    for (int r = 0; r < RH; ++r)
      #pragma unroll
      for (int j = 0; j < 2; ++j)
        #pragma unroll
        for (int kw = 0; kw < 2; ++kw)
          acc[RH + r][j] = __builtin_amdgcn_mfma_f32_16x16x32_f16(af[r][kw], bf[j][kw], acc[RH + r][j], 0, 0, 0);
    __builtin_amdgcn_s_setprio(0);
    __builtin_amdgcn_s_barrier();
    __builtin_amdgcn_sched_barrier(0);
    // ---- P(1,1): cols 2-3
    __builtin_amdgcn_s_setprio(1);
    #pragma unroll
    for (int r = 0; r < RH; ++r)
      #pragma unroll
      for (int j = 2; j < 4; ++j)
        #pragma unroll
        for (int kw = 0; kw < 2; ++kw)
          acc[RH + r][j] = __builtin_amdgcn_mfma_f32_16x16x32_f16(af[r][kw], bf[j][kw], acc[RH + r][j], 0, 0, 0);
    __builtin_amdgcn_s_setprio(0);
    __builtin_amdgcn_s_barrier();
    __builtin_amdgcn_sched_barrier(0);
    cur ^= 1;
  }

  #pragma unroll
  for (int f = 0; f < RF; ++f)
    #pragma unroll
    for (int j = 0; j < 4; ++j) {
      int col = n0 + wn * 64 + j * 16 + la;
      #pragma unroll
      for (int r = 0; r < 4; ++r) {
        int row = m0 + wm * (BM / 2) + f * 16 + lk * 4 + r;
        C[(size_t)row * N + col] = (CT)acc[f][j][r];
      }
    }
}

// ---------------- ba = (h*mask) @ W_ba in fp32 (precision-critical for g) ----------------
__global__ __launch_bounds__(256)
void ba_gemm(const float* __restrict__ h, const float* __restrict__ mask,
             const float* __restrict__ Wba, float* __restrict__ ba) {
  __shared__ float red[4][8][64];
  int r0 = blockIdx.x * 8;
  int c = threadIdx.x & 63, kc = threadIdx.x >> 6;
  float acc[8] = {};
  const float* wp = Wba + (size_t)(kc * 512) * 64 + c;
  const float* hp = h + (size_t)r0 * HIDD + kc * 512;
  for (int i = 0; i < 512; ++i) {
    float w = wp[(size_t)i * 64];
    #pragma unroll
    for (int r = 0; r < 8; ++r)
      acc[r] += hp[(size_t)r * HIDD + i] * w;
  }
  #pragma unroll
  for (int r = 0; r < 8; ++r) red[kc][r][c] = acc[r];
  __syncthreads();
  if (kc == 0) {
    #pragma unroll
    for (int r = 0; r < 8; ++r) {
      float s = red[0][r][c] + red[1][r][c] + red[2][r][c] + red[3][r][c];
      ba[(size_t)(r0 + r) * 64 + c] = s * mask[r0 + r];
    }
  }
}

// ---------------- conv(4-tap causal) + SiLU + l2norm, sliding-window over 16-row groups ----
// block = 4 units x 16 rows; lane owns 2 cols; 19-row window loaded ONCE into registers
// (vs 4x re-read per output in the old row-per-block version).
__global__ __launch_bounds__(256)
void conv_kernel(const _Float16* __restrict__ qkvz, const float* __restrict__ ck,
                 _Float16* __restrict__ qn, _Float16* __restrict__ kn,
                 _Float16* __restrict__ vb) {
  int bid = blockIdx.x;
  int ug = bid & 15, rg = bid >> 4;          // unit-group 0..15, row-group 0..255
  int row0 = rg * 16;                        // 2048 % 16 == 0 -> group never crosses batch
  int t0 = row0 & 2047;
  int lane = threadIdx.x & 63, wid = threadIdx.x >> 6;
  int u = ug * 4 + wid;
  int c, cc, hh;
  if (u < 16)      { hh = u;      c = hh * 768;                               cc = hh * 128; }
  else if (u < 32) { hh = u - 16; c = hh * 768 + 128;                         cc = 2048 + hh * 128; }
  else             { hh = u - 32; c = (hh >> 1) * 768 + 256 + (hh & 1) * 128; cc = 4096 + hh * 128; }
  f32x2 wt[4];
  #pragma unroll
  for (int j = 0; j < 4; ++j)
    wt[j] = *(const f32x2*)(ck + j * 8192 + cc + 2 * lane);
  // window rows row0-3 .. row0+15 (zero-pad t<0 within batch)
  f16x2 x[19];
  const _Float16* base = qkvz + (size_t)row0 * NQKV + c + 2 * lane;
  #pragma unroll
  for (int i = 0; i < 19; ++i) {
    if (t0 - 3 + i >= 0) x[i] = *(const f16x2*)(base + ((ptrdiff_t)i - 3) * NQKV);
    else { x[i][0] = (_Float16)0; x[i][1] = (_Float16)0; }
  }
  #pragma unroll
  for (int r = 0; r < 16; ++r) {
    float y0 = 0.f, y1 = 0.f;
    #pragma unroll
    for (int j = 0; j < 4; ++j) {
      y0 += (float)x[r + j][0] * wt[j][0];
      y1 += (float)x[r + j][1] * wt[j][1];
    }
    y0 = y0 / (1.f + __expf(-y0));
    y1 = y1 / (1.f + __expf(-y1));
    int row = row0 + r;
    if (u < 32) {
      float ss = y0 * y0 + y1 * y1;
      #pragma unroll
      for (int m = 1; m < 64; m <<= 1) ss += __shfl_xor(ss, m);
      float rs = rsqrtf(ss + 1e-6f);
      if (u < 16) rs *= 0.08838834764831845f;   // DK^-0.5
      y0 *= rs; y1 *= rs;
      _Float16* dst = (u < 16 ? qn : kn) + (size_t)row * 2048 + hh * 128;
      f16x2 o; o[0] = (_Float16)y0; o[1] = (_Float16)y1;
      *(f16x2*)(dst + 2 * lane) = o;
    } else {
      _Float16* dst = vb + (size_t)row * 4096 + hh * 128;
      f16x2 o; o[0] = (_Float16)y0; o[1] = (_Float16)y1;
      *(f16x2*)(dst + 2 * lane) = o;
    }
  }
}

// ---------------- g/beta from fp32 ba; outputs TRANSPOSED [vh][b*2048+t] ----------------
__global__ __launch_bounds__(256)
void egbeta_kernel(const float* __restrict__ ba, const float* __restrict__ Alog,
                   const float* __restrict__ dtb, float* __restrict__ gout,
                   float* __restrict__ bout) {
  int i = blockIdx.x * 256 + threadIdx.x;     // MROWS*32
  if (i >= MROWS * 32) return;
  int vh = i >> 12, row = i & 4095;
  int kh = vh >> 1, r = vh & 1;
  const float* p = ba + (size_t)row * 64 + kh * 4;
  float bv = p[r], av = p[2 + r];
  float x = av + dtb[vh];
  float sp = (x > 20.f) ? x : log1pf(expf(x));
  gout[(size_t)vh * MROWS + row] = -expf(Alog[vh]) * sp;
  bout[(size_t)vh * MROWS + row] = 1.f / (1.f + expf(-bv));
}

// ---------------- chunked gated delta-rule scan (UT transform, MFMA, 8 waves) ----------------
__global__ __launch_bounds__(512, 2)
void chunk_scan(const _Float16* __restrict__ qn, const _Float16* __restrict__ kn,
                _Float16* __restrict__ vb, const float* __restrict__ gb,
                const float* __restrict__ btb) {
  __shared__ __align__(16) _Float16 Ks[64 * 128];   // [t][k] swz256
  __shared__ __align__(16) _Float16 Qs[64 * 128];   // [t][k] swz256
  __shared__ __align__(16) _Float16 Kt[128 * 64];   // [k][s] swz128
  __shared__ __align__(16) _Float16 Sf[32 * 128];   // [v][k] f16 state copy, swz256
  __shared__ float AT[64 * 65];                     // AT[s][t] = A[t][s]
  __shared__ __align__(16) _Float16 M16[64 * 64];   // [t][s] swz128
  __shared__ float RHS[32 * 65];                    // [v][t]
  __shared__ __align__(16) _Float16 Uv[32 * 64];    // [v][s] swz128 (raw u)
  __shared__ __align__(16) _Float16 Ub[32 * 64];    // [v][s] swz128 (u * scU[s])
  __shared__ __align__(16) _Float16 Vb[64 * 32];    // [t][v] linear, 64B rows
  __shared__ float gs[64], bs[64], cgs[64], bexp[64], scU[64];

  char* Ksb = (char*)Ks; char* Qsb = (char*)Qs; char* Ktb = (char*)Kt;
  char* Sfb = (char*)Sf; char* M16b = (char*)M16;
  char* Uvb = (char*)Uv; char* Ubb = (char*)Ub; char* Vbb = (char*)Vb;

  int bid = blockIdx.x;
  int b = bid >> 7, vh = (bid >> 2) & 31, vsl = bid & 3;
  int kh = vh >> 1;
  int tid = threadIdx.x;
  int w = tid >> 6, lane = tid & 63;
  int wr = w >> 1, wc = w & 1;
  int la = lane & 15, lk = lane >> 4;

  const _Float16* kgb = kn + (size_t)(b * 2048) * 2048 + kh * 128;
  const _Float16* qgb = qn + (size_t)(b * 2048) * 2048 + kh * 128;
  _Float16*       vgb = vb + (size_t)(b * 2048) * 4096 + vh * 128 + vsl * 32;
  const float*    ggb = gb  + (size_t)vh * MROWS + b * 2048;
  const float*    bgb = btb + (size_t)vh * MROWS + b * 2048;

  int srow = tid >> 3, sseg = tid & 7;
  int tk = tid & 127, tth = tid >> 7;

  f16x8 kr[2], qr[2]; f16x4 vr; float ebr;
  float sreg[2][4] = {};                 // S[v = vt*16+lk*4+r][k = w*16+la]

  { f32x4 z = {}; ((f32x4*)Sf)[tid] = z; }

  kr[0] = *(const f16x8*)(kgb + (size_t)srow * 2048 + sseg * 16);
  kr[1] = *(const f16x8*)(kgb + (size_t)srow * 2048 + sseg * 16 + 8);
  qr[0] = *(const f16x8*)(qgb + (size_t)srow * 2048 + sseg * 16);
  qr[1] = *(const f16x8*)(qgb + (size_t)srow * 2048 + sseg * 16 + 8);
  vr    = *(const f16x4*)(vgb + (size_t)srow * 4096 + sseg * 4);
  ebr   = (tid < 64) ? ggb[tid] : (tid < 128 ? bgb[tid - 64] : 0.f);
  *(f16x8*)(Ksb + swz256(srow, sseg * 32))      = kr[0];
  *(f16x8*)(Ksb + swz256(srow, sseg * 32 + 16)) = kr[1];
  *(f16x8*)(Qsb + swz256(srow, sseg * 32))      = qr[0];
  *(f16x8*)(Qsb + swz256(srow, sseg * 32 + 16)) = qr[1];
  *(f16x4*)(Vbb + srow * 64 + sseg * 8) = vr;
  if (tid < 64) gs[tid] = ebr; else if (tid < 128) bs[tid - 64] = ebr;
  __syncthreads();

  #pragma unroll 1
  for (int c = 0; c < NCHUNK; ++c) {
    int cn = (c < NCHUNK - 1) ? c + 1 : c;
    kr[0] = *(const f16x8*)(kgb + (size_t)(cn * 64 + srow) * 2048 + sseg * 16);
    kr[1] = *(const f16x8*)(kgb + (size_t)(cn * 64 + srow) * 2048 + sseg * 16 + 8);
    qr[0] = *(const f16x8*)(qgb + (size_t)(cn * 64 + srow) * 2048 + sseg * 16);
    qr[1] = *(const f16x8*)(qgb + (size_t)(cn * 64 + srow) * 2048 + sseg * 16 + 8);
    vr    = *(const f16x4*)(vgb + (size_t)(cn * 64 + srow) * 4096 + sseg * 4);
    ebr   = (tid < 64) ? ggb[cn * 64 + tid] : (tid < 128 ? bgb[cn * 64 + tid - 64] : 0.f);

    f32x4 kk[2] = {}, qk[2] = {}, ks0 = {}, qs0 = {};
    #pragma unroll
    for (int ks = 0; ks < 4; ++ks) {
      f16x8 aK = *(const f16x8*)(Ksb + swz256(wr * 16 + la, ks * 64 + lk * 16));
      f16x8 aQ = *(const f16x8*)(Qsb + swz256(wr * 16 + la, ks * 64 + lk * 16));
      f16x8 bS = *(const f16x8*)(Sfb + swz256(wc * 16 + la, ks * 64 + lk * 16));
      #pragma unroll
      for (int j = 0; j < 2; ++j) {
        f16x8 bK = *(const f16x8*)(Ksb + swz256(wc * 32 + j * 16 + la, ks * 64 + lk * 16));
        kk[j] = __builtin_amdgcn_mfma_f32_16x16x32_f16(aK, bK, kk[j], 0, 0, 0);
        qk[j] = __builtin_amdgcn_mfma_f32_16x16x32_f16(aQ, bK, qk[j], 0, 0, 0);
      }
      ks0 = __builtin_amdgcn_mfma_f32_16x16x32_f16(aK, bS, ks0, 0, 0, 0);
      qs0 = __builtin_amdgcn_mfma_f32_16x16x32_f16(aQ, bS, qs0, 0, 0, 0);
    }
    {
      f16x8 r0, r1;
      #pragma unroll
      for (int j = 0; j < 8; ++j) {
        r0[j] = *(const _Float16*)(Ksb + swz256(tth * 16 + j, 2 * tk));
        r1[j] = *(const _Float16*)(Ksb + swz256(tth * 16 + 8 + j, 2 * tk));
      }
      *(f16x8*)(Ktb + swz128(tk, tth * 32))      = r0;
      *(f16x8*)(Ktb + swz128(tk, tth * 32 + 16)) = r1;
    }
    if (w == 0) {
      float g = gs[lane];
      #pragma unroll
      for (int off = 1; off < 64; off <<= 1) {
        float y = __shfl_up(g, off);
        if (lane >= off) g += y;
      }
      cgs[lane] = g;
      float cgL = __shfl(g, 63);
      bexp[lane] = __expf(g);
      scU[lane] = bs[lane] * __expf(cgL - g);
    }
    __syncthreads();   // B1

    {
      float cgt[4];
      #pragma unroll
      for (int r = 0; r < 4; ++r) cgt[r] = cgs[wr * 16 + lk * 4 + r];
      #pragma unroll
      for (int j = 0; j < 2; ++j) {
        int s = wc * 32 + j * 16 + la;
        float bsv = bs[s], cgss = cgs[s];
        #pragma unroll
        for (int r = 0; r < 4; ++r) {
          int t = wr * 16 + lk * 4 + r;
          float e = bsv * __expf(cgt[r] - cgss);
          AT[s * 65 + t] = (s < t) ? e * kk[j][r] : 0.f;
          float mm = (s <= t) ? e * qk[j][r] : 0.f;
          *(_Float16*)(M16b + swz128(t, s * 2)) = (_Float16)mm;
        }
      }
      #pragma unroll
      for (int r = 0; r < 4; ++r) {
        int t = wr * 16 + lk * 4 + r;
        int v = wc * 16 + la;
        float be = bexp[t];
        qs0[r] *= be;
        float vv = (float)*(const _Float16*)(Vbb + t * 64 + v * 2);
        RHS[v * 65 + t] = vv - be * ks0[r];
      }
    }
    __syncthreads();   // B2

    {
      float u[4];
      #pragma unroll
      for (int vi = 0; vi < 4; ++vi) u[vi] = RHS[(w * 4 + vi) * 65 + lane];
      #pragma unroll 1
      for (int sb = 0; sb < 8; ++sb) {
        float Ac[8];
        #pragma unroll
        for (int j = 0; j < 8; ++j) Ac[j] = AT[(sb * 8 + j) * 65 + lane];
        #pragma unroll
        for (int j = 0; j < 8; ++j) {
          int s = sb * 8 + j;
          #pragma unroll
          for (int vi = 0; vi < 4; ++vi) {
            float ubv = __builtin_bit_cast(float,
                __builtin_amdgcn_readlane(__builtin_bit_cast(int, u[vi]), s));
            u[vi] = fmaf(-Ac[j], ubv, u[vi]);
          }
        }
      }
      float sc = scU[lane];
      #pragma unroll
      for (int vi = 0; vi < 4; ++vi) {
        int v = w * 4 + vi;
        *(_Float16*)(Uvb + swz128(v, lane * 2)) = (_Float16)u[vi];
        *(_Float16*)(Ubb + swz128(v, lane * 2)) = (_Float16)(u[vi] * sc);
      }
    }
    __syncthreads();   // B3

    #pragma unroll
    for (int ss = 0; ss < 2; ++ss) {
      f16x8 aM = *(const f16x8*)(M16b + swz128(wr * 16 + la, ss * 64 + lk * 16));
      f16x8 bU = *(const f16x8*)(Uvb + swz128(wc * 16 + la, ss * 64 + lk * 16));
      qs0 = __builtin_amdgcn_mfma_f32_16x16x32_f16(aM, bU, qs0, 0, 0, 0);
    }
    #pragma unroll
    for (int r = 0; r < 4; ++r) {
      int t = wr * 16 + lk * 4 + r;
      vgb[(size_t)(c * 64 + t) * 4096 + wc * 16 + la] = (_Float16)qs0[r];  // in-place: v[t] dead
    }
    {
      f32x4 sd[2] = {};
      #pragma unroll
      for (int ss = 0; ss < 2; ++ss) {
        f16x8 bK = *(const f16x8*)(Ktb + swz128(w * 16 + la, ss * 64 + lk * 16));
        #pragma unroll
        for (int vt = 0; vt < 2; ++vt) {
          f16x8 aU = *(const f16x8*)(Ubb + swz128(vt * 16 + la, ss * 64 + lk * 16));
          sd[vt] = __builtin_amdgcn_mfma_f32_16x16x32_f16(aU, bK, sd[vt], 0, 0, 0);
        }
      }
      float beC = bexp[63];
      #pragma unroll
      for (int vt = 0; vt < 2; ++vt)
        #pragma unroll
        for (int r = 0; r < 4; ++r) {
          int v = vt * 16 + lk * 4 + r;
          int k = w * 16 + la;
          float sn = fmaf(sreg[vt][r], beC, sd[vt][r]);
          sreg[vt][r] = sn;
          *(_Float16*)(Sfb + swz256(v, k * 2)) = (_Float16)sn;
        }
    }
    __syncthreads();   // B4

    *(f16x8*)(Ksb + swz256(srow, sseg * 32))      = kr[0];
    *(f16x8*)(Ksb + swz256(srow, sseg * 32 + 16)) = kr[1];
    *(f16x8*)(Qsb + swz256(srow, sseg * 32))      = qr[0];
    *(f16x8*)(Qsb + swz256(srow, sseg * 32 + 16)) = qr[1];
    *(f16x4*)(Vbb + srow * 64 + sseg * 8) = vr;
    if (tid < 64) gs[tid] = ebr; else if (tid < 128) bs[tid - 64] = ebr;
    __syncthreads();   // B5
  }
}

// ---------------- RMSNorm * norm_kernel * silu(z) -> fp16 Ag ----------------
__global__ __launch_bounds__(256)
void gate_kernel(const _Float16* __restrict__ ob, const _Float16* __restrict__ qkvz,
                 const float* __restrict__ nk, _Float16* __restrict__ Ag) {
  int row = blockIdx.x;
  int lane = threadIdx.x & 63, wid = threadIdx.x >> 6;
  for (int vh = wid; vh < 32; vh += 4) {
    const _Float16* op = ob + (size_t)row * 4096 + vh * 128;
    f16x2 xx = *(const f16x2*)(op + 2 * lane);
    float x0 = (float)xx[0], x1 = (float)xx[1];
    float ss = x0 * x0 + x1 * x1;
    #pragma unroll
    for (int m = 1; m < 64; m <<= 1) ss += __shfl_xor(ss, m);
    float rs = rsqrtf(ss * (1.f / 128.f) + 1e-6f);
    f32x2 nv = *(const f32x2*)(nk + 2 * lane);
    float v0 = x0 * rs * nv[0], v1 = x1 * rs * nv[1];
    const _Float16* zp = qkvz + (size_t)row * NQKV + (vh >> 1) * 768 + 512 + (vh & 1) * 128;
    f16x2 zz = *(const f16x2*)(zp + 2 * lane);
    float z0 = (float)zz[0], z1 = (float)zz[1];
    v0 *= z0 / (1.f + expf(-z0));
    v1 *= z1 / (1.f + expf(-z1));
    _Float16* dst = Ag + (size_t)row * 4096 + vh * 128;
    f16x2 o; o[0] = (_Float16)v0; o[1] = (_Float16)v1;
    *(f16x2*)(dst + 2 * lane) = o;
  }
}

extern "C" void kernel_launch(void* const* d_in, const int* in_sizes, int n_in,
                              void* d_out, int out_size, void* d_ws, size_t ws_size,
                              hipStream_t stream) {
  const float* h     = (const float*)d_in[0];
  const float* mask  = (const float*)d_in[1];
  const float* Wqkvz = (const float*)d_in[2];
  const float* Wba   = (const float*)d_in[3];
  const float* ck    = (const float*)d_in[4];
  const float* Alog  = (const float*)d_in[5];
  const float* dtb   = (const float*)d_in[6];
  const float* nk    = (const float*)d_in[7];
  const float* Wout  = (const float*)d_in[8];
  float* out = (float*)d_out;

  char* w = (char*)d_ws;
  const size_t o_qkvz = 0;                         // 100,663,296  [gemm1 .. gate]
  const size_t o_A1   = 100663296;                 //  16,777,216  [amask .. gemm1]
  const size_t o_Bt1  = o_A1 + 16777216;           //  50,331,648  [transpose .. gemm1]
  const size_t o_ba   = o_Bt1 + 50331648;          //   1,048,576
  const size_t o_g    = o_ba + 1048576;            //     524,288
  const size_t o_bt   = o_g + 524288;              //     524,288
  const size_t total  = o_bt + 524288;             // 169,869,312 B = 162 MiB
  if (ws_size < total) return;

  _Float16* qkvz16 = (_Float16*)(w + o_qkvz);
  _Float16* A1     = (_Float16*)(w + o_A1);
  _Float16* Bt1    = (_Float16*)(w + o_Bt1);
  float*    ba32   = (float*)   (w + o_ba);
  float*    gbuf   = (float*)   (w + o_g);
  float*    btb    = (float*)   (w + o_bt);
  // aliases over dead regions:
  _Float16* qn16 = (_Float16*)(w + o_A1);                    // over A1 (dead after gemm1)
  _Float16* kn16 = (_Float16*)(w + o_Bt1);                   // over Bt1[0:16M)
  _Float16* vb16 = (_Float16*)(w + o_Bt1 + 16777216);        // over Bt1[16M:50M); o in-place
  _Float16* Ag   = (_Float16*)(w + o_A1);                    // over qn+kn (dead after scan)
  _Float16* Wt2  = (_Float16*)(w + 0);                       // over qkvz (dead after gate)

  amask_kernel<<<MROWS * HIDD / 4 / 256, 256, 0, stream>>>(h, mask, A1);
  transpose_f16<<<dim3(192, 32), 256, 0, stream>>>(Wqkvz, Bt1, HIDD, NQKV);
  ba_gemm<<<MROWS / 8, 256, 0, stream>>>(h, mask, Wba, ba32);
  gemm8p<_Float16, 256><<<16 * 48, 512, 0, stream>>>(A1, Bt1, qkvz16, MROWS, NQKV, HIDD, 48);
  conv_kernel<<<4096, 256, 0, stream>>>(qkvz16, ck, qn16, kn16, vb16);
  egbeta_kernel<<<MROWS * 32 / 256, 256, 0, stream>>>(ba32, Alog, dtb, gbuf, btb);
  chunk_scan<<<256, 512, 0, stream>>>(qn16, kn16, vb16, gbuf, btb);
  gate_kernel<<<MROWS, 256, 0, stream>>>(vb16, qkvz16, nk, Ag);
  transpose_f16<<<dim3(32, 64), 256, 0, stream>>>(Wout, Wt2, 4096, HIDD);
  gemm8p<float, 128><<<32 * 8, 512, 0, stream>>>(Ag, Wt2, out, MROWS, HIDD, 4096, 8);
}